// Round 6
// baseline (269.805 us; speedup 1.0000x reference)
//
#include <hip/hip_runtime.h>
#include <hip/hip_bf16.h>

#define N_NODES 50000
#define E_EDGES 800000
#define IN_F    128
#define OUT_F   64
#define HEADS   4
#define HF      (HEADS * OUT_F)   // 256
#define NEG_SLOPE 0.2f
#define EPS     1e-8f
#define CAP     64                 // padded CSR slots per dst; deg ~ Poisson(16), P(>64)~5e-19
#define SLICE_F 32                 // features per (head,half) slice
#define NB_INIT ((N_NODES + 255) / 256)   // 196 init blocks

typedef __attribute__((ext_vector_type(8))) short bf16x8;
typedef __attribute__((ext_vector_type(4))) float f32x4;
typedef __attribute__((ext_vector_type(2))) float f32x2;

__device__ __forceinline__ unsigned short f2bf(float f) {
    return __hip_bfloat16_raw(__float2bfloat16(f)).x;
}
__device__ __forceinline__ float bf2f(unsigned short u) {
    return __uint_as_float((unsigned)u << 16);
}

// ---------------- Kernel 0: W -> bf16 transposed + cnt zeroing --------------
__global__ __launch_bounds__(256) void wcvt_kernel(
    const float* __restrict__ W,      // [H][IN_F][OUT_F]
    short* __restrict__ Wtb,          // [H][OUT_F][IN_F] bf16 bits
    int* __restrict__ cnt)            // [N] -> 0
{
    const int i = blockIdx.x * 256 + threadIdx.x;
    if (i < N_NODES) cnt[i] = 0;
    if (i < HEADS * IN_F * OUT_F) {
        const int h  = i >> 13;
        const int fl = (i >> 7) & 63;
        const int k  = i & 127;
        Wtb[i] = (short)f2bf(W[h * (IN_F * OUT_F) + k * OUT_F + fl]);
    }
}

// ---------------- Kernel 1: MFMA projection + logits + FUSED scatter --------
// One block per 16 nodes (3125 blocks), 4 waves; wave w = head w.
// Whb is written SLICE-MAJOR: slice p = h*2+half (8 slices of N x 32 bf16,
// 3.2 MB each) so the aggregate kernel's gathers are XCD-local L2 hits.
__global__ __launch_bounds__(256) void proj_kernel(
    const float* __restrict__ x,      // [N][IN_F]
    const short* __restrict__ Wtb,    // [H][OUT_F][IN_F] bf16
    const float* __restrict__ a_src,  // [H][OUT_F]
    const float* __restrict__ a_dst,  // [H][OUT_F]
    const int* __restrict__ src,      // [E]
    const int* __restrict__ dst,      // [E]
    unsigned short* __restrict__ Whb, // [8][N][SLICE_F] bf16 (slice-major)
    float* __restrict__ esrc,         // [N][H]
    float* __restrict__ edst,         // [N][H]
    int* __restrict__ cnt,            // [N], zeroed by wcvt
    unsigned short* __restrict__ csr) // [N][CAP] src ids grouped by dst
{
    __shared__ short xs[16][136];              // bf16 x tile (all waves read)
    __shared__ unsigned short ot[4][16][72];   // per-WAVE transpose buffer

    const int tid = threadIdx.x;
    const int n0 = blockIdx.x * 16;            // 3125 * 16 = 50000 exact

    // edge owned by this thread (3125*256 == E exact)
    const int e  = blockIdx.x * 256 + tid;
    const int de = dst[e];
    const int se = src[e];

    {
        const int row = tid >> 4;
        const int kb = (tid & 15) * 8;
        const float* xp = x + (size_t)(n0 + row) * IN_F + kb;
        const float4 x0 = *(const float4*)(xp);
        const float4 x1 = *(const float4*)(xp + 4);
        bf16x8 v;
        v[0] = (short)f2bf(x0.x); v[1] = (short)f2bf(x0.y);
        v[2] = (short)f2bf(x0.z); v[3] = (short)f2bf(x0.w);
        v[4] = (short)f2bf(x1.x); v[5] = (short)f2bf(x1.y);
        v[6] = (short)f2bf(x1.z); v[7] = (short)f2bf(x1.w);
        *(bf16x8*)&xs[row][kb] = v;
    }
    __syncthreads();

    // claim padded-CSR slot: result consumed only at the kernel tail
    const int pos = atomicAdd(&cnt[de], 1);

    const int h = tid >> 6;
    const int lane = tid & 63;
    const int c = lane & 15;
    const int quad = lane >> 4;

    bf16x8 a[4];
#pragma unroll
    for (int ks = 0; ks < 4; ++ks)
        a[ks] = *(const bf16x8*)&xs[c][ks * 32 + quad * 8];

    f32x4 acc[4];
#pragma unroll
    for (int nt = 0; nt < 4; ++nt) acc[nt] = (f32x4){0.f, 0.f, 0.f, 0.f};

    const short* Wh_head = Wtb + (h << 13);
#pragma unroll
    for (int nt = 0; nt < 4; ++nt) {
        const short* wrow = Wh_head + ((nt * 16 + c) << 7) + (quad << 3);
#pragma unroll
        for (int ks = 0; ks < 4; ++ks) {
            const bf16x8 b = *(const bf16x8*)(wrow + (ks << 5));
            acc[nt] = __builtin_amdgcn_mfma_f32_16x16x32_bf16(a[ks], b, acc[nt], 0, 0, 0);
        }
    }

    float ps[4] = {0.f, 0.f, 0.f, 0.f};
    float pd[4] = {0.f, 0.f, 0.f, 0.f};
#pragma unroll
    for (int nt = 0; nt < 4; ++nt) {
        const float as = a_src[h * OUT_F + nt * 16 + c];
        const float ad = a_dst[h * OUT_F + nt * 16 + c];
#pragma unroll
        for (int r = 0; r < 4; ++r) {
            ps[r] += acc[nt][r] * as;
            pd[r] += acc[nt][r] * ad;
        }
    }
#pragma unroll
    for (int m = 1; m < 16; m <<= 1) {
#pragma unroll
        for (int r = 0; r < 4; ++r) {
            ps[r] += __shfl_xor(ps[r], m);
            pd[r] += __shfl_xor(pd[r], m);
        }
    }
    if (c == 0) {
#pragma unroll
        for (int r = 0; r < 4; ++r) {
            const int n = n0 + quad * 4 + r;
            esrc[n * HEADS + h] = ps[r];
            edst[n * HEADS + h] = pd[r];
        }
    }

    // per-wave transpose: acc(row=quad*4+r, feat=nt*16+c) -> contiguous rows
#pragma unroll
    for (int nt = 0; nt < 4; ++nt) {
#pragma unroll
        for (int r = 0; r < 4; ++r)
            ot[h][quad * 4 + r][nt * 16 + c] = f2bf(acc[nt][r]);
    }
    // wave-synchronous LDS visibility (same wave wrote it)
    {
        const int row = lane >> 2;            // 0..15
        const int co  = (lane & 3) * 16;      // 16 shorts = 32B per lane
        const int sl  = (h << 1) + (co >> 5); // slice = h*2 + half
        unsigned short* gp = Whb + ((size_t)sl * N_NODES + (n0 + row)) * SLICE_F + (co & 31);
        const unsigned short* sp = &ot[h][row][co];
        *(int4*)(gp)     = *(const int4*)(sp);      // shorts 0..7
        *(int4*)(gp + 8) = *(const int4*)(sp + 8);  // shorts 8..15
    }

    // dependent scatter store: atomic long retired by now
    if (pos < CAP)
        __builtin_nontemporal_store((unsigned short)se, &csr[(size_t)de * CAP + pos]);
}

// ---------------- Kernel 2: fused softmax + aggregation (XCD-sliced) --------
// Partition p = blockIdx & 7 maps to XCD p (dispatch round-robin). Each
// partition gathers ONLY its 3.2-MB Whb slice -> slice stays resident in
// that XCD's 4-MB L2. Wave = one dst: 64 lanes = 4 edge-slots x 16 lanes;
// each 16-lane group reads one full 64-B slice row per edge (single line).
__global__ __launch_bounds__(256) void aggregate_kernel(
    const int* __restrict__ cnt,      // [N]
    const unsigned short* __restrict__ csr, // [N][CAP]
    const float* __restrict__ esrc,   // [N][H]
    const float* __restrict__ edst,   // [N][H]
    const unsigned short* __restrict__ Whb, // [8][N][SLICE_F] bf16
    float* __restrict__ out)          // [N][H*OUT_F]
{
    __shared__ unsigned short ssb[4][64];
    __shared__ float spb[4][64];

    const int wid  = threadIdx.x >> 6;
    const int lane = threadIdx.x & 63;
    const int p = blockIdx.x & 7;          // partition <-> XCD
    const int h = p >> 1;
    const int d = (blockIdx.x >> 3) * 4 + wid;   // 12500*4 = 50000 exact

    int deg = cnt[d];
    deg = deg > CAP ? CAP : deg;

    const float edh = edst[d * HEADS + h];

    float lsum = 0.f;
    unsigned short sfill = 0;
    float pfill = 0.f;
    if (lane < deg) {
        const int s = (int)csr[(size_t)d * CAP + lane];
        float v = esrc[s * HEADS + h] + edh;
        v = v > 0.f ? v : NEG_SLOPE * v;
        pfill = __expf(v);
        lsum = pfill;
        sfill = (unsigned short)s;
    }
    ssb[wid][lane] = sfill;                // padded lanes: row 0, weight 0
    spb[wid][lane] = pfill;
    // wave-synchronous LDS visibility (same wave wrote it)

    const unsigned short* wslice =
        Whb + (size_t)p * N_NODES * SLICE_F + ((lane & 15) << 1);
    const int j0 = lane >> 4;              // edge-slot within wave

    float a0 = 0.f, a1 = 0.f;
#pragma unroll 4
    for (int i = 0; i < deg; i += 4) {
        const int   s = (int)ssb[wid][i + j0];
        const float q = spb[wid][i + j0];
        const ushort2 w = *(const ushort2*)(wslice + (unsigned)s * SLICE_F);
        a0 += q * bf2f(w.x);
        a1 += q * bf2f(w.y);
    }
    // reduce across the 4 edge-slot groups (lanes differ in bits 4,5)
    a0 += __shfl_xor(a0, 16); a0 += __shfl_xor(a0, 32);
    a1 += __shfl_xor(a1, 16); a1 += __shfl_xor(a1, 32);
    // lsum over all 64 lanes (one p per lane)
#pragma unroll
    for (int m = 1; m < 64; m <<= 1) lsum += __shfl_xor(lsum, m);
    const float r = 1.f / (lsum + EPS);

    if (lane < 16) {
        const f32x2 o2 = {a0 * r, a1 * r};
        float* op = out + (size_t)d * HF + (h << 6) + ((p & 1) << 5) + (lane << 1);
        __builtin_nontemporal_store(o2, (f32x2*)op);
    }
}

extern "C" void kernel_launch(void* const* d_in, const int* in_sizes, int n_in,
                              void* d_out, int out_size, void* d_ws, size_t ws_size,
                              hipStream_t stream) {
    const float* x      = (const float*)d_in[0];
    const int*   eidx   = (const int*)d_in[1];     // [2][E]
    const float* W      = (const float*)d_in[2];
    const float* a_src  = (const float*)d_in[3];
    const float* a_dst  = (const float*)d_in[4];
    float* out = (float*)d_out;

    const int* src = eidx;
    const int* dst = eidx + E_EDGES;

    // workspace layout (~34 MB total, all 64-B aligned)
    unsigned short* Whb = (unsigned short*)d_ws;                  // 8*N*32 bf16 (25.6 MB)
    float* esrc   = (float*)(Whb + (size_t)8 * N_NODES * SLICE_F);// N*H (0.8 MB)
    float* edst   = esrc + (size_t)N_NODES * HEADS;               // N*H (0.8 MB)
    int*   cnt    = (int*)(edst + (size_t)N_NODES * HEADS);       // N (0.2 MB)
    unsigned short* csr = (unsigned short*)(cnt + N_NODES);       // N*CAP u16 (6.4 MB)
    short* Wtb    = (short*)(csr + (size_t)N_NODES * CAP);        // H*OUT_F*IN_F bf16 (64 KB)

    wcvt_kernel<<<NB_INIT, 256, 0, stream>>>(W, Wtb, cnt);

    proj_kernel<<<N_NODES / 16, 256, 0, stream>>>(x, Wtb, a_src, a_dst, src, dst,
                                                  Whb, esrc, edst, cnt, csr);

    aggregate_kernel<<<(N_NODES / 4) * 8, 256, 0, stream>>>(cnt, csr, esrc, edst, Whb, out);
}